// Round 1
// baseline (31234.247 us; speedup 1.0000x reference)
//
#include <hip/hip_runtime.h>
#include <math.h>

#define SN 512   // seq len / steps
#define BN 128   // samples
#define EN 256   // embed dim
#define HN 256   // hidden dim
#define G4 1024  // 4*H
#define CLIPV 10.0f

// ---- workspace layout (float offsets) ----
#define OFF_EPT    ((size_t)0)                      // enc_proj^T [H][S]  : 256*512
#define OFF_XPROJ  (OFF_EPT   + (size_t)256*512)    // X_proj [S][1024]
#define OFF_WHHT   (OFF_XPROJ + (size_t)512*1024)   // W_hh^T [H][1024]
#define OFF_WADT   (OFF_WHHT  + (size_t)256*1024)   // Wa_dec^T [H][H]
#define OFF_WIHT   (OFF_WADT  + (size_t)256*256)    // W_ih^T [E][1024]
#define OFF_XT     (OFF_WIHT  + (size_t)256*1024)   // x^T [E][S]
#define OFF_BIAS   (OFF_XT    + (size_t)256*512)    // b_ih+b_hh [1024]
#define OFF_IPROJ  (OFF_BIAS  + (size_t)1024)       // W_ih@init_dec [1024]
// total = 1378304 floats = ~5.3 MB

__device__ __forceinline__ float tanh_fast(float x) {
    // tanh via hardware exp2 + rcp; ~2 ulp. (t = e^{-2|x|}; r=(1-t)/(1+t))
    float a = fabsf(x);
    float e = __builtin_amdgcn_exp2f(a * -2.8853900817779268f); // -2*log2(e)
    float r = (1.0f - e) * __builtin_amdgcn_rcpf(1.0f + e);
    return copysignf(r, x);
}

// ---------------- init kernel 1: transposes + bias ----------------
__global__ __launch_bounds__(256) void k_init_transpose(
    const float* __restrict__ Wih, const float* __restrict__ Whh,
    const float* __restrict__ Wad, const float* __restrict__ bih,
    const float* __restrict__ bhh, const float* __restrict__ x,
    float* __restrict__ ws)
{
    float* wiht = ws + OFF_WIHT;
    float* whht = ws + OFF_WHHT;
    float* wadt = ws + OFF_WADT;
    float* xt   = ws + OFF_XT;
    float* bias = ws + OFF_BIAS;
    int i = blockIdx.x * 256 + threadIdx.x;
    if (i < 262144) {                       // W_ih^T [e][r]
        int e = i >> 10, r = i & 1023;
        wiht[i] = Wih[(size_t)r * 256 + e];
    } else if (i < 524288) {                // W_hh^T [k][r]
        int j = i - 262144; int k = j >> 10, r = j & 1023;
        whht[j] = Whh[(size_t)r * 256 + k];
    } else if (i < 589824) {                // Wa_dec^T [k][r]
        int j = i - 524288; int k = j >> 8, r = j & 255;
        wadt[j] = Wad[(size_t)r * 256 + k];
    } else if (i < 720896) {                // x^T [e][s]
        int j = i - 589824; int e = j >> 9, s = j & 511;
        xt[j] = x[(size_t)s * 256 + e];
    } else if (i < 721920) {                // bias
        int j = i - 720896;
        bias[j] = bih[j] + bhh[j];
    }
}

// ---------------- init kernel 2: projections (double-accum) ----------------
__global__ __launch_bounds__(512) void k_init_proj(
    const float* __restrict__ x, const float* __restrict__ Wae,
    const float* __restrict__ ba, const float* __restrict__ idec,
    float* __restrict__ ws)
{
    const float* wiht = ws + OFF_WIHT;
    const float* xt   = ws + OFF_XT;
    float* ept   = ws + OFF_EPT;
    float* xproj = ws + OFF_XPROJ;
    float* iproj = ws + OFF_IPROJ;
    int blk = blockIdx.x, tid = threadIdx.x;
    if (blk < 256) {
        // enc_proj^T[k][s] = b_a[k] + sum_e Wa_enc[k][e] * x[s][e]
        int k = blk, s = tid;
        double a = 0.0;
        for (int e = 0; e < 256; ++e)
            a += (double)Wae[(size_t)k * 256 + e] * (double)xt[(size_t)e * 512 + s];
        ept[(size_t)k * 512 + s] = (float)((double)ba[k] + a);
    } else if (blk < 256 + 1024) {
        // X_proj[s][r] = sum_e x[s][e] * W_ih[r][e]
        int idx = blk - 256;
        int s = idx >> 1;
        int r = (idx & 1) * 512 + tid;
        double a = 0.0;
        for (int e = 0; e < 256; ++e)
            a += (double)x[(size_t)s * 256 + e] * (double)wiht[(size_t)e * 1024 + r];
        xproj[(size_t)s * 1024 + r] = (float)a;
    } else {
        // init_proj[r] = sum_e init_dec[e] * W_ih[r][e]
        int r = (blk - 1280) * 512 + tid;
        double a = 0.0;
        for (int e = 0; e < 256; ++e)
            a += (double)idec[e] * (double)wiht[(size_t)e * 1024 + r];
        iproj[r] = (float)a;
    }
}

// ---------------- main persistent decode kernel: 1 WG per sample ----------------
__global__ __launch_bounds__(1024) void k_decode(
    const float* __restrict__ gmb, const float* __restrict__ vvec,
    const float* __restrict__ ws, float* __restrict__ out)
{
    const float* ept   = ws + OFF_EPT;
    const float* xproj = ws + OFF_XPROJ;
    const float* whht  = ws + OFF_WHHT;
    const float* wadt  = ws + OFF_WADT;
    const float* bias  = ws + OFF_BIAS;
    const float* iproj = ws + OFF_IPROJ;

    __shared__ __align__(16) float  h[HN];
    __shared__ __align__(16) float  c[HN];
    __shared__ __align__(16) float  hWa[HN];
    __shared__ __align__(16) double vLd[HN];
    __shared__ __align__(16) float  gates[G4];
    __shared__ __align__(16) float  lmask[SN];
    __shared__ __align__(16) float  maskadd[SN];
    __shared__ __align__(16) double pp[8 * SN];   // 32 KB: attention partials (also hWa partials)
    __shared__ int selS;

    const int b = blockIdx.x;
    const int tid = threadIdx.x;

    for (int i = tid; i < HN; i += 1024) { h[i] = 0.f; c[i] = 0.f; vLd[i] = (double)vvec[i]; }
    for (int i = tid; i < SN; i += 1024) { maskadd[i] = 0.f; }
    if (tid == 0) selS = 0;
    __syncthreads();

    float lps = 0.f;  // maintained by wave 0 (replicated across its lanes)
    const float4* ept4 = reinterpret_cast<const float4*>(ept);

    for (int t = 0; t < SN; ++t) {
        // ---- phase 1: gates[r] = bias[r] + X_proj[sel][r] + sum_k W_hh^T[k][r]*h[k]
        {
            const float* xr = (t == 0) ? iproj : (xproj + (size_t)selS * G4);
            int r = tid;
            const float* wcol = whht + r;
            float a0 = 0.f, a1 = 0.f, a2 = 0.f, a3 = 0.f;
            for (int k = 0; k < HN; k += 4) {
                float4 hv = *reinterpret_cast<const float4*>(&h[k]);
                a0 = fmaf(wcol[(size_t)(k + 0) * G4], hv.x, a0);
                a1 = fmaf(wcol[(size_t)(k + 1) * G4], hv.y, a1);
                a2 = fmaf(wcol[(size_t)(k + 2) * G4], hv.z, a2);
                a3 = fmaf(wcol[(size_t)(k + 3) * G4], hv.w, a3);
            }
            gates[r] = bias[r] + xr[r] + ((a0 + a1) + (a2 + a3));
        }
        __syncthreads();

        // ---- phase 2: LSTM cell update (torch gate order i,f,g,o)
        if (tid < HN) {
            int j = tid;
            float gi = gates[j], gf = gates[j + HN], gg = gates[j + 2 * HN], go = gates[j + 3 * HN];
            float si = 1.0f / (1.0f + expf(-gi));
            float sf = 1.0f / (1.0f + expf(-gf));
            float so = 1.0f / (1.0f + expf(-go));
            float p1 = sf * c[j];
            float p2 = si * tanhf(gg);
            float cf = p1 + p2;
            float hf = so * tanhf(cf);
            c[j] = cf; h[j] = hf;
        }
        __syncthreads();

        // ---- phase 3: hWa[r] = sum_k Wa_dec^T[k][r]*h[k]   (double partials, 4-way k split)
        {
            int r = tid & (HN - 1), q = tid >> 8;   // q in 0..3
            const float* wc = wadt + r;
            double a = 0.0;
            int k0 = q * 64;
            for (int k = k0; k < k0 + 64; ++k)
                a += (double)wc[(size_t)k * HN] * (double)h[k];
            pp[(size_t)q * HN + r] = a;
        }
        __syncthreads();
        if (tid < HN) {
            double s4 = (pp[tid] + pp[HN + tid]) + (pp[2 * HN + tid] + pp[3 * HN + tid]);
            hWa[tid] = (float)s4;
        }
        __syncthreads();

        // ---- phase 4: u[s] = sum_k v[k]*tanh(hWa[k] + ep^T[k][s]); logits = 10*tanh(u)
        {
            int sidx = tid & 127, kh = tid >> 7;    // 128 s-blocks of 4, 8 k-groups of 32
            double a0 = 0, a1 = 0, a2 = 0, a3 = 0;
            int k0 = kh * 32;
            for (int k = k0; k < k0 + 32; ++k) {
                float4 ev = ept4[(size_t)k * 128 + sidx];
                float hv = hWa[k];
                double vv = vLd[k];
                a0 += vv * (double)tanh_fast(ev.x + hv);
                a1 += vv * (double)tanh_fast(ev.y + hv);
                a2 += vv * (double)tanh_fast(ev.z + hv);
                a3 += vv * (double)tanh_fast(ev.w + hv);
            }
            double2* pw = reinterpret_cast<double2*>(&pp[(size_t)kh * SN + sidx * 4]);
            pw[0] = make_double2(a0, a1);
            pw[1] = make_double2(a2, a3);
        }
        __syncthreads();
        if (tid < SN) {
            int s = tid;
            double u = ((pp[0 * SN + s] + pp[1 * SN + s]) + (pp[2 * SN + s] + pp[3 * SN + s]))
                     + ((pp[4 * SN + s] + pp[5 * SN + s]) + (pp[6 * SN + s] + pp[7 * SN + s]));
            float lg = (float)(10.0 * tanh(u));
            lmask[s] = lg + maskadd[s];   // masked entries: finite + (-inf) = -inf
        }
        __syncthreads();

        // ---- phase 5: wave 0 does masked log-softmax + Gumbel argmax + state update
        if (tid < 64) {
            const float* grow = gmb + (size_t)t * (BN * SN) + (size_t)b * SN;
            float lv[8];
            float M = -INFINITY;
            #pragma unroll
            for (int j = 0; j < 8; ++j) { lv[j] = lmask[tid + 64 * j]; M = fmaxf(M, lv[j]); }
            #pragma unroll
            for (int off = 32; off >= 1; off >>= 1) M = fmaxf(M, __shfl_xor(M, off, 64));
            float se = 0.f;
            #pragma unroll
            for (int j = 0; j < 8; ++j) se += expf(lv[j] - M);   // exp(-inf)=0
            #pragma unroll
            for (int off = 32; off >= 1; off >>= 1) se += __shfl_xor(se, off, 64);
            float logS = logf(se);
            float best = -INFINITY; int bidx = 0x7fffffff; float blp = 0.f;
            #pragma unroll
            for (int j = 0; j < 8; ++j) {
                int s = tid + 64 * j;
                float lp = (lv[j] - M) - logS;          // matches jax log_softmax rounding
                float cd = lp + grow[s];
                if (cd > best || (cd == best && s < bidx)) { best = cd; bidx = s; blp = lp; }
            }
            #pragma unroll
            for (int off = 32; off >= 1; off >>= 1) {
                float ob = __shfl_xor(best, off, 64);
                int   oi = __shfl_xor(bidx, off, 64);
                float ol = __shfl_xor(blp, off, 64);
                if (ob > best || (ob == best && oi < bidx)) { best = ob; bidx = oi; blp = ol; }
            }
            lps += blp;
            if (tid == 0) {
                selS = bidx;
                maskadd[bidx] = -INFINITY;
                out[(size_t)b * SN + t] = (float)bidx;   // predicted_mappings[b][t]
            }
        }
        __syncthreads();
    }
    if (tid == 0) out[(size_t)BN * SN + b] = lps;        // log_probs_sum[b]
}

extern "C" void kernel_launch(void* const* d_in, const int* in_sizes, int n_in,
                              void* d_out, int out_size, void* d_ws, size_t ws_size,
                              hipStream_t stream)
{
    const float* x    = (const float*)d_in[0];
    const float* gmb  = (const float*)d_in[1];
    const float* Wih  = (const float*)d_in[2];
    const float* Whh  = (const float*)d_in[3];
    const float* bih  = (const float*)d_in[4];
    const float* bhh  = (const float*)d_in[5];
    const float* Wad  = (const float*)d_in[6];
    const float* Wae  = (const float*)d_in[7];
    const float* ba   = (const float*)d_in[8];
    const float* vvec = (const float*)d_in[9];
    const float* idec = (const float*)d_in[10];
    float* ws = (float*)d_ws;
    float* out = (float*)d_out;

    hipLaunchKernelGGL(k_init_transpose, dim3(2820), dim3(256), 0, stream,
                       Wih, Whh, Wad, bih, bhh, x, ws);
    hipLaunchKernelGGL(k_init_proj, dim3(1282), dim3(512), 0, stream,
                       x, Wae, ba, idec, ws);
    hipLaunchKernelGGL(k_decode, dim3(BN), dim3(1024), 0, stream,
                       gmb, vvec, ws, out);
}